// Round 1
// baseline (348.158 us; speedup 1.0000x reference)
//
#include <hip/hip_runtime.h>
#include <hip/hip_bf16.h>

typedef __attribute__((ext_vector_type(8))) short short8;
typedef __attribute__((ext_vector_type(4))) float f32x4;
typedef __attribute__((ext_vector_type(2))) float f32x2;

#define LOG2E 1.44269504088896340736f

__device__ __forceinline__ unsigned short f2bf(float f) {
  unsigned u = __builtin_bit_cast(unsigned, f);
  u += 0x7fffu + ((u >> 16) & 1u);
  return (unsigned short)(u >> 16);
}

__device__ __forceinline__ float fast_sigmoid(float x) {
  return __builtin_amdgcn_rcpf(1.0f + __builtin_amdgcn_exp2f(-LOG2E * x));
}
__device__ __forceinline__ float fast_tanh(float x) {
  float e = __builtin_amdgcn_exp2f(2.0f * LOG2E * x);
  return 1.0f - 2.0f * __builtin_amdgcn_rcpf(e + 1.0f);
}

// -------------------- setup: fold input projections into gather tables ----
__global__ void ptab_kernel(
    const float* __restrict__ E_time, const float* __restrict__ E_week,
    const float* __restrict__ Wh_x, const float* __restrict__ bh,
    const float* __restrict__ Ww_x, const float* __restrict__ bw,
    float* __restrict__ Ptime, float* __restrict__ Pweek)
{
  const int c = threadIdx.x;      // 0..383
  const int rid = blockIdx.x;     // 0..30
  if (rid < 24) {
    float acc = bh[c];
    for (int d = 0; d < 128; ++d)
      acc = fmaf(E_time[rid * 128 + d], Wh_x[d * 384 + c], acc);
    Ptime[rid * 384 + c] = acc;
  } else {
    const int r = rid - 24;
    float acc = bw[c];
    for (int d = 0; d < 128; ++d)
      acc = fmaf(E_week[r * 128 + d], Ww_x[d * 384 + c], acc);
    Pweek[r * 384 + c] = acc;
  }
}

// -------------------- setup: MLP weights -> transposed bf16 [N][K] --------
__global__ void wconv_kernel(
    const float* __restrict__ W1, const float* __restrict__ W2,
    const float* __restrict__ W3, const float* __restrict__ W4,
    unsigned short* __restrict__ Wt)
{
  const int id = blockIdx.x * 256 + threadIdx.x;   // 0..819199
  float v;
  if (id < 131072) {                 // W1t [1024][128]
    const int off = id, n = off >> 7, k = off & 127;
    v = W1[k * 1024 + n];
    Wt[off] = f2bf(v);
  } else if (id < 655360) {          // W2t [512][1024]
    const int off = id - 131072, n = off >> 10, k = off & 1023;
    v = W2[k * 512 + n];
    Wt[id] = f2bf(v);
  } else if (id < 786432) {          // W3t [256][512]
    const int off = id - 655360, n = off >> 9, k = off & 511;
    v = W3[k * 256 + n];
    Wt[id] = f2bf(v);
  } else {                           // W4t [128][256]
    const int off = id - 786432, n = off >> 8, k = off & 255;
    v = W4[k * 128 + n];
    Wt[id] = f2bf(v);
  }
}

// -------------------- persistent GRU kernel -------------------------------
// grid 192 = 3 GRUs x 64 chunks of 16 batch rows. 512 threads = 8 waves.
// Wave w owns output cols [w*48, w*48+48): 3 MFMA tiles, Wh frags in regs.
__global__ __launch_bounds__(512) void gru_kernel(
    const float* __restrict__ spatial,
    const int* __restrict__ hour_idx,
    const int* __restrict__ week_idx,
    const float* __restrict__ Ws_x,
    const float* __restrict__ Ws_h, const float* __restrict__ bs,
    const float* __restrict__ Wh_h, const float* __restrict__ bh,
    const float* __restrict__ Ww_h, const float* __restrict__ bw,
    const float* __restrict__ Ptime, const float* __restrict__ Pweek,
    float* __restrict__ fs, float* __restrict__ fh, float* __restrict__ fw)
{
  __shared__ __align__(16) unsigned short h_bf[16 * 136];   // stride 136 (pad)
  __shared__ __align__(16) float hp_T[384 * 20];            // [col][row], stride 20 (pad)
  __shared__ __align__(16) float xinfo[16 * 256 * 2];       // spatial [t][i][2] OR idx [t][i]
  __shared__ __align__(16) float ptab[24 * 384];            // P table (gru 1/2)

  const int tid  = threadIdx.x;
  const int lane = tid & 63;
  const int wv   = tid >> 6;
  const int gid  = blockIdx.x;
  const int gru  = gid >> 6;
  const int row0 = (gid & 63) * 16;

  const float* __restrict__ Wh   = (gru == 0) ? Ws_h : (gru == 1) ? Wh_h : Ww_h;
  const float* __restrict__ bvec = (gru == 0) ? bs   : (gru == 1) ? bh   : bw;
  float* __restrict__ fout       = (gru == 0) ? fs   : (gru == 1) ? fh   : fw;

  // gate-thread fixed indices: col j, rows ib..ib+3
  const int j  = tid & 127;
  const int ib = (tid >> 7) * 4;

  const float b1z = bvec[384 + j];
  const float b1r = bvec[384 + 128 + j];
  const float b1n = bvec[384 + 256 + j];

  float w0z = 0, w0r = 0, w0n = 0, w1z = 0, w1r = 0, w1n = 0;
  float b0z = 0, b0r = 0, b0n = 0;
  if (gru == 0) {
    w0z = Ws_x[j];       w0r = Ws_x[128 + j];       w0n = Ws_x[256 + j];
    w1z = Ws_x[384 + j]; w1r = Ws_x[384 + 128 + j]; w1n = Ws_x[384 + 256 + j];
    b0z = bvec[j];       b0r = bvec[128 + j];       b0n = bvec[256 + j];
  }

  // load Wh fragments into registers (bf16), one-time
  const int ar  = lane & 15;        // A row / B col within tile
  const int akg = lane >> 4;        // k group
  short8 wfrag[3][4];
  {
    #pragma unroll
    for (int nt = 0; nt < 3; ++nt) {
      const int n = wv * 48 + nt * 16 + ar;
      #pragma unroll
      for (int ks = 0; ks < 4; ++ks) {
        const int k0 = ks * 32 + akg * 8;
        short8 f;
        #pragma unroll
        for (int q = 0; q < 8; ++q)
          f[q] = (short)f2bf(Wh[(k0 + q) * 384 + n]);
        wfrag[nt][ks] = f;
      }
    }
  }

  // preload per-step input info
  if (gru == 0) {
    for (int e = tid; e < 16 * 256; e += 512) {
      const int i = e >> 8, t = e & 255;
      const f32x2 v = *(const f32x2*)&spatial[((row0 + i) * 256 + t) * 2];
      *(f32x2*)&xinfo[(t * 16 + i) * 2] = v;
    }
  } else {
    const int* __restrict__ idxg = (gru == 1) ? hour_idx : week_idx;
    for (int e = tid; e < 16 * 256; e += 512) {
      const int i = e >> 8, t = e & 255;
      ((int*)xinfo)[t * 16 + i] = idxg[(row0 + i) * 256 + t];
    }
    const float* __restrict__ P = (gru == 1) ? Ptime : Pweek;
    const int np = (gru == 1) ? 24 * 384 : 7 * 384;
    for (int e = tid; e < np; e += 512) ptab[e] = P[e];
  }

  // h state (fp32 in regs) and bf16 copy in LDS, init 0
  for (int e = tid; e < 16 * 136; e += 512) h_bf[e] = 0;
  float h0 = 0.f, h1 = 0.f, h2 = 0.f, h3 = 0.f;
  __syncthreads();

  const int c0    = wv * 48 + ar;   // first tile's output col
  const int rb    = akg * 4;        // C-fragment row base
  const int abase = ar * 136;       // h_bf row base (shorts)

  for (int t = 0; t < 256; ++t) {
    // ---- MFMA phase: hp = h @ Wh (bf16 in, fp32 acc) ----
    f32x4 acc0 = {0.f, 0.f, 0.f, 0.f};
    f32x4 acc1 = {0.f, 0.f, 0.f, 0.f};
    f32x4 acc2 = {0.f, 0.f, 0.f, 0.f};
    #pragma unroll
    for (int ks = 0; ks < 4; ++ks) {
      const short8 a = *(const short8*)&h_bf[abase + ks * 32 + akg * 8];
      acc0 = __builtin_amdgcn_mfma_f32_16x16x32_bf16(a, wfrag[0][ks], acc0, 0, 0, 0);
      acc1 = __builtin_amdgcn_mfma_f32_16x16x32_bf16(a, wfrag[1][ks], acc1, 0, 0, 0);
      acc2 = __builtin_amdgcn_mfma_f32_16x16x32_bf16(a, wfrag[2][ks], acc2, 0, 0, 0);
    }
    *(f32x4*)&hp_T[(c0     ) * 20 + rb] = acc0;
    *(f32x4*)&hp_T[(c0 + 16) * 20 + rb] = acc1;
    *(f32x4*)&hp_T[(c0 + 32) * 20 + rb] = acc2;
    __syncthreads();

    // ---- gate phase (fp32) ----
    const f32x4 hz = *(const f32x4*)&hp_T[(      j) * 20 + ib];
    const f32x4 hr = *(const f32x4*)&hp_T[(128 + j) * 20 + ib];
    const f32x4 hn = *(const f32x4*)&hp_T[(256 + j) * 20 + ib];

    float xz[4], xr[4], xh[4];
    if (gru == 0) {
      #pragma unroll
      for (int r = 0; r < 4; ++r) {
        const f32x2 s = *(const f32x2*)&xinfo[(t * 16 + ib + r) * 2];
        xz[r] = b0z + s.x * w0z + s.y * w1z;
        xr[r] = b0r + s.x * w0r + s.y * w1r;
        xh[r] = b0n + s.x * w0n + s.y * w1n;
      }
    } else {
      #pragma unroll
      for (int r = 0; r < 4; ++r) {
        const int ix = ((const int*)xinfo)[t * 16 + ib + r];
        const float* __restrict__ pr = &ptab[ix * 384];
        xz[r] = pr[j]; xr[r] = pr[128 + j]; xh[r] = pr[256 + j];
      }
    }

    float hcur0 = h0, hcur1 = h1, hcur2 = h2, hcur3 = h3;
    float hv[4] = {hcur0, hcur1, hcur2, hcur3};
    float hnew[4];
    #pragma unroll
    for (int r = 0; r < 4; ++r) {
      const float z  = fast_sigmoid(xz[r] + hz[r] + b1z);
      const float rr = fast_sigmoid(xr[r] + hr[r] + b1r);
      const float hh = fast_tanh(xh[r] + rr * (hn[r] + b1n));
      hnew[r] = z * hv[r] + (1.f - z) * hh;
      h_bf[(ib + r) * 136 + j] = f2bf(hnew[r]);
    }
    h0 = hnew[0]; h1 = hnew[1]; h2 = hnew[2]; h3 = hnew[3];
    __syncthreads();
  }

  fout[(row0 + ib + 0) * 128 + j] = h0;
  fout[(row0 + ib + 1) * 128 + j] = h1;
  fout[(row0 + ib + 2) * 128 + j] = h2;
  fout[(row0 + ib + 3) * 128 + j] = h3;
}

// -------------------- fused attention + MLP -------------------------------
template<int K, int N>
__device__ __forceinline__ void mlp_layer(
    const unsigned short* __restrict__ xin, unsigned short* __restrict__ xout,
    const unsigned short* __restrict__ Wt, const float* __restrict__ bias,
    int lane, int wv, float* __restrict__ foutF)
{
  constexpr int NT = N / 64;
  const int ar  = lane & 15;
  const int akg = lane >> 4;
  f32x4 acc[NT];
  #pragma unroll
  for (int nt = 0; nt < NT; ++nt) acc[nt] = f32x4{0.f, 0.f, 0.f, 0.f};
  for (int ks = 0; ks < K / 32; ++ks) {
    const short8 a = *(const short8*)&xin[ar * 1032 + ks * 32 + akg * 8];
    #pragma unroll
    for (int nt = 0; nt < NT; ++nt) {
      const int n = wv * (N / 4) + nt * 16 + ar;
      const short8 b = *(const short8*)&Wt[n * K + ks * 32 + akg * 8];
      acc[nt] = __builtin_amdgcn_mfma_f32_16x16x32_bf16(a, b, acc[nt], 0, 0, 0);
    }
  }
  const int rbase = akg * 4;
  #pragma unroll
  for (int nt = 0; nt < NT; ++nt) {
    const int n = wv * (N / 4) + nt * 16 + ar;
    const float bv = bias[n];
    #pragma unroll
    for (int q = 0; q < 4; ++q) {
      float v = acc[nt][q] + bv;
      v = fmaxf(v, 0.f);
      xout[(rbase + q) * 1032 + n] = f2bf(v);
      if (foutF) foutF[(rbase + q) * 128 + n] = v;
    }
  }
}

__global__ __launch_bounds__(256) void attn_mlp_kernel(
    const float* __restrict__ fs, const float* __restrict__ fh, const float* __restrict__ fw,
    const float* __restrict__ Wa, const float* __restrict__ ba,
    const unsigned short* __restrict__ Wt,
    const float* __restrict__ b1, const float* __restrict__ b2,
    const float* __restrict__ b3, const float* __restrict__ b4,
    const float* __restrict__ Wo, const float* __restrict__ bo,
    float* __restrict__ out)
{
  __shared__ __align__(16) unsigned short xa[16 * 1032];
  __shared__ __align__(16) unsigned short xb[16 * 1032];
  __shared__ __align__(16) float sf_l[16 * 128];
  __shared__ __align__(16) float x4f[16 * 128];

  const int tid  = threadIdx.x;
  const int lane = tid & 63;
  const int wv   = tid >> 6;
  const int row0 = blockIdx.x * 16;

  // ---- attention over the 3 features ----
  {
    const int i  = tid >> 4;
    const int j0 = (tid & 15) * 8;
    float wa[9], bav[3];
    #pragma unroll
    for (int q = 0; q < 9; ++q) wa[q] = Wa[q];
    #pragma unroll
    for (int q = 0; q < 3; ++q) bav[q] = ba[q];
    const int base = (row0 + i) * 128 + j0;
    #pragma unroll
    for (int half = 0; half < 2; ++half) {
      const f32x4 a = *(const f32x4*)&fs[base + half * 4];
      const f32x4 b = *(const f32x4*)&fh[base + half * 4];
      const f32x4 c = *(const f32x4*)&fw[base + half * 4];
      #pragma unroll
      for (int q = 0; q < 4; ++q) {
        const float f0 = a[q], f1 = b[q], f2 = c[q];
        float s0 = f0 * wa[0] + f1 * wa[3] + f2 * wa[6] + bav[0];
        float s1 = f0 * wa[1] + f1 * wa[4] + f2 * wa[7] + bav[1];
        float s2 = f0 * wa[2] + f1 * wa[5] + f2 * wa[8] + bav[2];
        s0 = fmaxf(s0, 0.f); s1 = fmaxf(s1, 0.f); s2 = fmaxf(s2, 0.f);
        const float m  = fmaxf(s0, fmaxf(s1, s2));
        const float e0 = __builtin_amdgcn_exp2f((s0 - m) * LOG2E);
        const float e1 = __builtin_amdgcn_exp2f((s1 - m) * LOG2E);
        const float e2 = __builtin_amdgcn_exp2f((s2 - m) * LOG2E);
        const float inv = __builtin_amdgcn_rcpf(e0 + e1 + e2);
        const float sf  = (f0 * e0 + f1 * e1 + f2 * e2) * inv;
        const int jj = j0 + half * 4 + q;
        sf_l[i * 128 + jj] = sf;
        xa[i * 1032 + jj]  = f2bf(sf);
      }
    }
  }
  __syncthreads();

  mlp_layer<128, 1024>(xa, xb, Wt,          b1, lane, wv, nullptr);
  __syncthreads();
  mlp_layer<1024, 512>(xb, xa, Wt + 131072, b2, lane, wv, nullptr);
  __syncthreads();
  mlp_layer<512,  256>(xa, xb, Wt + 655360, b3, lane, wv, nullptr);
  __syncthreads();
  mlp_layer<256,  128>(xb, xa, Wt + 786432, b4, lane, wv, x4f);
  __syncthreads();

  // ---- residual + final Dense(1) ----
  const int row = tid >> 4;
  const int p   = tid & 15;
  float part = 0.f;
  #pragma unroll
  for (int q = 0; q < 8; ++q) {
    const int jj = p + q * 16;
    part += (x4f[row * 128 + jj] + sf_l[row * 128 + jj]) * Wo[jj];
  }
  #pragma unroll
  for (int off = 8; off > 0; off >>= 1)
    part += __shfl_xor(part, off, 16);
  if (p == 0) out[row0 + row] = part + bo[0];
}

// -------------------- launch ----------------------------------------------
extern "C" void kernel_launch(void* const* d_in, const int* in_sizes, int n_in,
                              void* d_out, int out_size, void* d_ws, size_t ws_size,
                              hipStream_t stream) {
  const float* spatial  = (const float*)d_in[0];
  const int*   hour_idx = (const int*)d_in[1];
  const int*   week_idx = (const int*)d_in[2];
  const float* E_time   = (const float*)d_in[3];
  const float* E_week   = (const float*)d_in[4];
  const float* Ws_x = (const float*)d_in[5];
  const float* Ws_h = (const float*)d_in[6];
  const float* bs   = (const float*)d_in[7];
  const float* Wh_x = (const float*)d_in[8];
  const float* Wh_h = (const float*)d_in[9];
  const float* bh   = (const float*)d_in[10];
  const float* Ww_x = (const float*)d_in[11];
  const float* Ww_h = (const float*)d_in[12];
  const float* bw   = (const float*)d_in[13];
  const float* Wa   = (const float*)d_in[14];
  const float* ba   = (const float*)d_in[15];
  const float* W1   = (const float*)d_in[16];
  const float* b1   = (const float*)d_in[17];
  const float* W2   = (const float*)d_in[18];
  const float* b2   = (const float*)d_in[19];
  const float* W3   = (const float*)d_in[20];
  const float* b3   = (const float*)d_in[21];
  const float* W4   = (const float*)d_in[22];
  const float* b4   = (const float*)d_in[23];
  const float* Wo   = (const float*)d_in[24];
  const float* bo   = (const float*)d_in[25];
  float* out = (float*)d_out;

  float* ws    = (float*)d_ws;
  float* Ptime = ws;                     // 24*384 = 9216
  float* Pweek = Ptime + 9216;           // 7*384  = 2688
  float* fsb   = Pweek + 2688;           // 1024*128
  float* fhb   = fsb + 131072;
  float* fwb   = fhb + 131072;
  unsigned short* Wt = (unsigned short*)(fwb + 131072);  // 819200 bf16

  ptab_kernel<<<31, 384, 0, stream>>>(E_time, E_week, Wh_x, bh, Ww_x, bw, Ptime, Pweek);
  wconv_kernel<<<3200, 256, 0, stream>>>(W1, W2, W3, W4, Wt);
  gru_kernel<<<192, 512, 0, stream>>>(spatial, hour_idx, week_idx, Ws_x,
      Ws_h, bs, Wh_h, bh, Ww_h, bw, Ptime, Pweek, fsb, fhb, fwb);
  attn_mlp_kernel<<<64, 256, 0, stream>>>(fsb, fhb, fwb, Wa, ba, Wt,
      b1, b2, b3, b4, Wo, bo, out);
}

// Round 2
// 264.408 us; speedup vs baseline: 1.3167x; 1.3167x over previous
//
#include <hip/hip_runtime.h>
#include <hip/hip_bf16.h>

typedef __attribute__((ext_vector_type(8))) short short8;
typedef __attribute__((ext_vector_type(4))) float f32x4;
typedef __attribute__((ext_vector_type(2))) float f32x2;

#define LOG2E  1.44269504088896340736f
#define NLOG2E (-1.44269504088896340736f)
#define TLOG2E (2.88539008177792681472f)

__device__ __forceinline__ unsigned short f2bf(float f) {
  unsigned u = __builtin_bit_cast(unsigned, f);
  u += 0x7fffu + ((u >> 16) & 1u);
  return (unsigned short)(u >> 16);
}

// -------------------- merged setup: P tables + MLP weight transpose -------
// blocks 0..30: ptab rows (24 time + 7 week). blocks 31..: wconv.
__global__ void setup_kernel(
    const float* __restrict__ E_time, const float* __restrict__ E_week,
    const float* __restrict__ Wh_x, const float* __restrict__ bh,
    const float* __restrict__ Ww_x, const float* __restrict__ bw,
    const float* __restrict__ W1, const float* __restrict__ W2,
    const float* __restrict__ W3, const float* __restrict__ W4,
    float* __restrict__ Ptime, float* __restrict__ Pweek,
    unsigned short* __restrict__ Wt)
{
  const int b = blockIdx.x;
  const int tid = threadIdx.x;
  if (b < 31) {
    const int c = tid;            // 0..383
    if (b < 24) {
      float acc = bh[c];
      for (int d = 0; d < 128; ++d)
        acc = fmaf(E_time[b * 128 + d], Wh_x[d * 384 + c], acc);
      Ptime[b * 384 + c] = acc;
    } else {
      const int r = b - 24;
      float acc = bw[c];
      for (int d = 0; d < 128; ++d)
        acc = fmaf(E_week[r * 128 + d], Ww_x[d * 384 + c], acc);
      Pweek[r * 384 + c] = acc;
    }
    return;
  }
  const int id = (b - 31) * 384 + tid;
  if (id >= 819200) return;
  if (id < 131072) {                 // W1t [1024][128]
    const int n = id >> 7, k = id & 127;
    Wt[id] = f2bf(W1[k * 1024 + n]);
  } else if (id < 655360) {          // W2t [512][1024]
    const int off = id - 131072, n = off >> 10, k = off & 1023;
    Wt[id] = f2bf(W2[k * 512 + n]);
  } else if (id < 786432) {          // W3t [256][512]
    const int off = id - 655360, n = off >> 9, k = off & 511;
    Wt[id] = f2bf(W3[k * 256 + n]);
  } else {                           // W4t [128][256]
    const int off = id - 786432, n = off >> 8, k = off & 255;
    Wt[id] = f2bf(W4[k * 128 + n]);
  }
}

// -------------------- persistent GRU kernel v2 ----------------------------
// grid 192 = 3 GRUs x 64 chunks of 16 rows. 512 threads = 8 waves.
// Wave w owns col triple {w*16.., 128+w*16.., 256+w*16..}: gates in-register,
// ONE barrier/step, h double-buffered in LDS. exp-scales folded into weights.
__global__ __launch_bounds__(512) void gru_kernel(
    const float* __restrict__ spatial,
    const int* __restrict__ hour_idx,
    const int* __restrict__ week_idx,
    const float* __restrict__ Ws_x,
    const float* __restrict__ Ws_h, const float* __restrict__ bs,
    const float* __restrict__ Wh_h, const float* __restrict__ bh,
    const float* __restrict__ Ww_h, const float* __restrict__ bw,
    const float* __restrict__ Ptime, const float* __restrict__ Pweek,
    float* __restrict__ fs, float* __restrict__ fh, float* __restrict__ fw)
{
  __shared__ __align__(16) unsigned short h_bf[2][16 * 136];
  __shared__ __align__(16) float ptab3[24 * 387 + 1];      // [ix][j*3+g]
  __shared__ __align__(16) float xsp[256 * 16 * 2];        // spatial [t][i][2]
  __shared__ __align__(16) unsigned char idx8[256 * 16];   // [t][i]

  const int tid  = threadIdx.x;
  const int lane = tid & 63;
  const int wv   = tid >> 6;       // 0..7
  const int ar   = lane & 15;
  const int akg  = lane >> 4;      // 0..3
  const int gid  = blockIdx.x;
  const int gru  = gid >> 6;
  const int row0 = (gid & 63) * 16;

  const float* __restrict__ Wh   = (gru == 0) ? Ws_h : (gru == 1) ? Wh_h : Ww_h;
  const float* __restrict__ bvec = (gru == 0) ? bs   : (gru == 1) ? bh   : bw;
  float* __restrict__ fout       = (gru == 0) ? fs   : (gru == 1) ? fh   : fw;

  const int j = wv * 16 + ar;      // hidden col 0..127 owned by this lane
  const float gsc[3] = {NLOG2E, NLOG2E, TLOG2E};

  // Wh B-fragments (scaled, bf16) in registers for all 256 steps
  short8 wfrag[3][4];
  #pragma unroll
  for (int g = 0; g < 3; ++g) {
    const int n = g * 128 + j;
    #pragma unroll
    for (int ks = 0; ks < 4; ++ks) {
      const int k0 = ks * 32 + akg * 8;
      short8 f;
      #pragma unroll
      for (int q = 0; q < 8; ++q)
        f[q] = (short)f2bf(Wh[(k0 + q) * 384 + n] * gsc[g]);
      wfrag[g][ks] = f;
    }
  }

  // b1 biases folded (scaled) into accumulator init
  const float bz = bvec[384 +       j] * NLOG2E;
  const float br = bvec[384 + 128 + j] * NLOG2E;
  const float bn = bvec[384 + 256 + j] * TLOG2E;

  // spatial-GRU x weights (scaled)
  float w0g[3] = {0, 0, 0}, w1g[3] = {0, 0, 0}, b0g[3] = {0, 0, 0};
  if (gru == 0) {
    #pragma unroll
    for (int g = 0; g < 3; ++g) {
      w0g[g] = Ws_x[      g * 128 + j] * gsc[g];
      w1g[g] = Ws_x[384 + g * 128 + j] * gsc[g];
      b0g[g] = bvec[      g * 128 + j] * gsc[g];
    }
  }

  // ---- preload per-step input info ----
  if (gru == 0) {
    for (int e = tid; e < 16 * 256; e += 512) {
      const int i = e >> 8, t = e & 255;
      const f32x2 v = *(const f32x2*)&spatial[((row0 + i) * 256 + t) * 2];
      *(f32x2*)&xsp[(t * 16 + i) * 2] = v;
    }
  } else {
    const int* __restrict__ idxg = (gru == 1) ? hour_idx : week_idx;
    for (int e = tid; e < 16 * 256; e += 512) {
      const int i = e >> 8, t = e & 255;
      idx8[t * 16 + i] = (unsigned char)idxg[(row0 + i) * 256 + t];
    }
    const float* __restrict__ P = (gru == 1) ? Ptime : Pweek;
    const int nr = (gru == 1) ? 24 : 7;
    for (int e = tid; e < nr * 384; e += 512) {
      const int ix = e / 384, c = e - ix * 384;
      const int g = c >> 7, jj = c & 127;
      ptab3[ix * 387 + jj * 3 + g] = P[e] * gsc[g];
    }
  }
  for (int e = tid; e < 16 * 136; e += 512) h_bf[0][e] = 0;

  // x-part prefetch (one step ahead): xp[r][g] = scaled x-projection
  auto loadx = [&](int t, float (&xp)[4][3]) {
    if (gru == 0) {
      #pragma unroll
      for (int r2 = 0; r2 < 4; ++r2) {
        const f32x2 s = *(const f32x2*)&xsp[(t * 16 + akg * 4 + r2) * 2];
        #pragma unroll
        for (int g = 0; g < 3; ++g)
          xp[r2][g] = fmaf(s.y, w1g[g], fmaf(s.x, w0g[g], b0g[g]));
      }
    } else {
      const unsigned pk = *(const unsigned*)&idx8[t * 16 + akg * 4];
      #pragma unroll
      for (int r2 = 0; r2 < 4; ++r2) {
        const int ix = (pk >> (8 * r2)) & 255;
        const float* __restrict__ p = &ptab3[ix * 387 + j * 3];
        xp[r2][0] = p[0]; xp[r2][1] = p[1]; xp[r2][2] = p[2];
      }
    }
  };

  __syncthreads();

  float hst[4] = {0.f, 0.f, 0.f, 0.f};
  float xpc[4][3];
  loadx(0, xpc);
  int cur = 0;

  #pragma unroll 2
  for (int t = 0; t < 256; ++t) {
    // ---- MFMA: hp = h @ Wh' (+b1'), in-register C fragments ----
    f32x4 accz = {bz, bz, bz, bz};
    f32x4 accr = {br, br, br, br};
    f32x4 accn = {bn, bn, bn, bn};
    const unsigned short* __restrict__ hb = h_bf[cur];
    #pragma unroll
    for (int ks = 0; ks < 4; ++ks) {
      const short8 a = *(const short8*)&hb[ar * 136 + ks * 32 + akg * 8];
      accz = __builtin_amdgcn_mfma_f32_16x16x32_bf16(a, wfrag[0][ks], accz, 0, 0, 0);
      accr = __builtin_amdgcn_mfma_f32_16x16x32_bf16(a, wfrag[1][ks], accr, 0, 0, 0);
      accn = __builtin_amdgcn_mfma_f32_16x16x32_bf16(a, wfrag[2][ks], accn, 0, 0, 0);
    }

    // ---- prefetch next step's x while MFMA/gates run ----
    float xpn[4][3];
    if (t < 255) loadx(t + 1, xpn);

    // ---- gates fully in-register ----
    float hn4[4];
    #pragma unroll
    for (int r2 = 0; r2 < 4; ++r2) {
      const float z  = __builtin_amdgcn_rcpf(1.f + __builtin_amdgcn_exp2f(xpc[r2][0] + accz[r2]));
      const float rr = __builtin_amdgcn_rcpf(1.f + __builtin_amdgcn_exp2f(xpc[r2][1] + accr[r2]));
      const float e  = __builtin_amdgcn_exp2f(fmaf(rr, accn[r2], xpc[r2][2]));
      const float hh = fmaf(-2.f, __builtin_amdgcn_rcpf(e + 1.f), 1.f);
      hn4[r2] = fmaf(z, hst[r2] - hh, hh);
      hst[r2] = hn4[r2];
    }

    // ---- pack to bf16, write h for next step (other buffer) ----
    unsigned p01, p23;
    asm("v_cvt_pk_bf16_f32 %0, %1, %2" : "=v"(p01) : "v"(hn4[0]), "v"(hn4[1]));
    asm("v_cvt_pk_bf16_f32 %0, %1, %2" : "=v"(p23) : "v"(hn4[2]), "v"(hn4[3]));
    unsigned short* __restrict__ ho = h_bf[cur ^ 1];
    ho[(akg * 4 + 0) * 136 + j] = (unsigned short)(p01 & 0xffffu);
    ho[(akg * 4 + 1) * 136 + j] = (unsigned short)(p01 >> 16);
    ho[(akg * 4 + 2) * 136 + j] = (unsigned short)(p23 & 0xffffu);
    ho[(akg * 4 + 3) * 136 + j] = (unsigned short)(p23 >> 16);

    __syncthreads();
    cur ^= 1;
    #pragma unroll
    for (int r2 = 0; r2 < 4; ++r2) {
      xpc[r2][0] = xpn[r2][0]; xpc[r2][1] = xpn[r2][1]; xpc[r2][2] = xpn[r2][2];
    }
  }

  #pragma unroll
  for (int r2 = 0; r2 < 4; ++r2)
    fout[(row0 + akg * 4 + r2) * 128 + j] = hst[r2];
}

// -------------------- fused attention + MLP -------------------------------
template<int K, int N>
__device__ __forceinline__ void mlp_layer(
    const unsigned short* __restrict__ xin, unsigned short* __restrict__ xout,
    const unsigned short* __restrict__ Wt, const float* __restrict__ bias,
    int lane, int wv, float* __restrict__ foutF)
{
  constexpr int NT = N / 64;
  const int ar  = lane & 15;
  const int akg = lane >> 4;
  f32x4 acc[NT];
  #pragma unroll
  for (int nt = 0; nt < NT; ++nt) acc[nt] = f32x4{0.f, 0.f, 0.f, 0.f};
  for (int ks = 0; ks < K / 32; ++ks) {
    const short8 a = *(const short8*)&xin[ar * 1032 + ks * 32 + akg * 8];
    #pragma unroll
    for (int nt = 0; nt < NT; ++nt) {
      const int n = wv * (N / 4) + nt * 16 + ar;
      const short8 b = *(const short8*)&Wt[n * K + ks * 32 + akg * 8];
      acc[nt] = __builtin_amdgcn_mfma_f32_16x16x32_bf16(a, b, acc[nt], 0, 0, 0);
    }
  }
  const int rbase = akg * 4;
  #pragma unroll
  for (int nt = 0; nt < NT; ++nt) {
    const int n = wv * (N / 4) + nt * 16 + ar;
    const float bv = bias[n];
    #pragma unroll
    for (int q = 0; q < 4; ++q) {
      float v = acc[nt][q] + bv;
      v = fmaxf(v, 0.f);
      xout[(rbase + q) * 1032 + n] = f2bf(v);
      if (foutF) foutF[(rbase + q) * 128 + n] = v;
    }
  }
}

__global__ __launch_bounds__(256) void attn_mlp_kernel(
    const float* __restrict__ fs, const float* __restrict__ fh, const float* __restrict__ fw,
    const float* __restrict__ Wa, const float* __restrict__ ba,
    const unsigned short* __restrict__ Wt,
    const float* __restrict__ b1, const float* __restrict__ b2,
    const float* __restrict__ b3, const float* __restrict__ b4,
    const float* __restrict__ Wo, const float* __restrict__ bo,
    float* __restrict__ out)
{
  __shared__ __align__(16) unsigned short xa[16 * 1032];
  __shared__ __align__(16) unsigned short xb[16 * 1032];
  __shared__ __align__(16) float sf_l[16 * 128];
  __shared__ __align__(16) float x4f[16 * 128];

  const int tid  = threadIdx.x;
  const int lane = tid & 63;
  const int wv   = tid >> 6;
  const int row0 = blockIdx.x * 16;

  {
    const int i  = tid >> 4;
    const int j0 = (tid & 15) * 8;
    float wa[9], bav[3];
    #pragma unroll
    for (int q = 0; q < 9; ++q) wa[q] = Wa[q];
    #pragma unroll
    for (int q = 0; q < 3; ++q) bav[q] = ba[q];
    const int base = (row0 + i) * 128 + j0;
    #pragma unroll
    for (int half = 0; half < 2; ++half) {
      const f32x4 a = *(const f32x4*)&fs[base + half * 4];
      const f32x4 b = *(const f32x4*)&fh[base + half * 4];
      const f32x4 c = *(const f32x4*)&fw[base + half * 4];
      #pragma unroll
      for (int q = 0; q < 4; ++q) {
        const float f0 = a[q], f1 = b[q], f2 = c[q];
        float s0 = f0 * wa[0] + f1 * wa[3] + f2 * wa[6] + bav[0];
        float s1 = f0 * wa[1] + f1 * wa[4] + f2 * wa[7] + bav[1];
        float s2 = f0 * wa[2] + f1 * wa[5] + f2 * wa[8] + bav[2];
        s0 = fmaxf(s0, 0.f); s1 = fmaxf(s1, 0.f); s2 = fmaxf(s2, 0.f);
        const float m  = fmaxf(s0, fmaxf(s1, s2));
        const float e0 = __builtin_amdgcn_exp2f((s0 - m) * LOG2E);
        const float e1 = __builtin_amdgcn_exp2f((s1 - m) * LOG2E);
        const float e2 = __builtin_amdgcn_exp2f((s2 - m) * LOG2E);
        const float inv = __builtin_amdgcn_rcpf(e0 + e1 + e2);
        const float sf  = (f0 * e0 + f1 * e1 + f2 * e2) * inv;
        const int jj = j0 + half * 4 + q;
        sf_l[i * 128 + jj] = sf;
        xa[i * 1032 + jj]  = f2bf(sf);
      }
    }
  }
  __syncthreads();

  mlp_layer<128, 1024>(xa, xb, Wt,          b1, lane, wv, nullptr);
  __syncthreads();
  mlp_layer<1024, 512>(xb, xa, Wt + 131072, b2, lane, wv, nullptr);
  __syncthreads();
  mlp_layer<512,  256>(xa, xb, Wt + 655360, b3, lane, wv, nullptr);
  __syncthreads();
  mlp_layer<256,  128>(xb, xa, Wt + 786432, b4, lane, wv, x4f);
  __syncthreads();

  const int row = tid >> 4;
  const int p   = tid & 15;
  float part = 0.f;
  #pragma unroll
  for (int q = 0; q < 8; ++q) {
    const int jj = p + q * 16;
    part += (x4f[row * 128 + jj] + sf_l[row * 128 + jj]) * Wo[jj];
  }
  #pragma unroll
  for (int off = 8; off > 0; off >>= 1)
    part += __shfl_xor(part, off, 16);
  if (p == 0) out[row0 + row] = part + bo[0];
}

// -------------------- launch ----------------------------------------------
extern "C" void kernel_launch(void* const* d_in, const int* in_sizes, int n_in,
                              void* d_out, int out_size, void* d_ws, size_t ws_size,
                              hipStream_t stream) {
  const float* spatial  = (const float*)d_in[0];
  const int*   hour_idx = (const int*)d_in[1];
  const int*   week_idx = (const int*)d_in[2];
  const float* E_time   = (const float*)d_in[3];
  const float* E_week   = (const float*)d_in[4];
  const float* Ws_x = (const float*)d_in[5];
  const float* Ws_h = (const float*)d_in[6];
  const float* bs   = (const float*)d_in[7];
  const float* Wh_x = (const float*)d_in[8];
  const float* Wh_h = (const float*)d_in[9];
  const float* bh   = (const float*)d_in[10];
  const float* Ww_x = (const float*)d_in[11];
  const float* Ww_h = (const float*)d_in[12];
  const float* bw   = (const float*)d_in[13];
  const float* Wa   = (const float*)d_in[14];
  const float* ba   = (const float*)d_in[15];
  const float* W1   = (const float*)d_in[16];
  const float* b1   = (const float*)d_in[17];
  const float* W2   = (const float*)d_in[18];
  const float* b2   = (const float*)d_in[19];
  const float* W3   = (const float*)d_in[20];
  const float* b3   = (const float*)d_in[21];
  const float* W4   = (const float*)d_in[22];
  const float* b4   = (const float*)d_in[23];
  const float* Wo   = (const float*)d_in[24];
  const float* bo   = (const float*)d_in[25];
  float* out = (float*)d_out;

  float* ws    = (float*)d_ws;
  float* Ptime = ws;                     // 24*384
  float* Pweek = Ptime + 9216;           // 7*384
  float* fsb   = Pweek + 2688;           // 1024*128
  float* fhb   = fsb + 131072;
  float* fwb   = fhb + 131072;
  unsigned short* Wt = (unsigned short*)(fwb + 131072);  // 819200 bf16

  setup_kernel<<<31 + 2134, 384, 0, stream>>>(E_time, E_week, Wh_x, bh, Ww_x, bw,
      W1, W2, W3, W4, Ptime, Pweek, Wt);
  gru_kernel<<<192, 512, 0, stream>>>(spatial, hour_idx, week_idx, Ws_x,
      Ws_h, bs, Wh_h, bh, Ww_h, bw, Ptime, Pweek, fsb, fhb, fwb);
  attn_mlp_kernel<<<64, 256, 0, stream>>>(fsb, fhb, fwb, Wa, ba, Wt,
      b1, b2, b3, b4, Wo, bo, out);
}